// Round 11
// baseline (192.211 us; speedup 1.0000x reference)
//
#include <hip/hip_runtime.h>

namespace {

constexpr int NNODES = 50000;
constexpr int NEDGES = 800000;
constexpr int NBUCK  = (NNODES + 127) / 128;  // 391 buckets of 128 dst nodes
constexpr int BCAP   = 3072;                  // bucket capacity: mean 2048, ~22 sigma slack
constexpr int SB     = 64;                    // mega-kernel blocks (co-resident: 64 << 256 CUs)
constexpr int CHUNK  = NEDGES / SB;           // 12500 edges per block (exact)

// ROUND-6: per-address global atomic ~140ns serialized -> never >1K ops/address.
// ROUND-7: aggregation must be node-parallel (50K waves), never bucket-parallel.
// ROUND-9: seg_mean is latency/issue-bound, not byte-bound.
// ROUND-10: ~11 serial dispatches cost ~25-35us in inter-kernel gaps; fuse the
// whole preprocessing chain into one co-resident kernel with grid barriers.

static __device__ __forceinline__ unsigned short f2bf(float f) {
  unsigned u = __float_as_uint(f);
  u += 0x7FFFu + ((u >> 16) & 1u);   // round-to-nearest-even
  return (unsigned short)(u >> 16);
}

// v_pk_fma_f32 with op_sel broadcast of one half of src0 (2 FMA/lane/cycle).
static __device__ __forceinline__ void pk_fma_lo(float2& d, const float2 a, const float2 b) {
  asm("v_pk_fma_f32 %0, %1, %2, %0 op_sel:[0,0,0] op_sel_hi:[0,1,1]"
      : "+v"(d) : "v"(a), "v"(b));
}
static __device__ __forceinline__ void pk_fma_hi(float2& d, const float2 a, const float2 b) {
  asm("v_pk_fma_f32 %0, %1, %2, %0 op_sel:[1,0,0] op_sel_hi:[1,1,1]"
      : "+v"(d) : "v"(a), "v"(b));
}

// Device-scope grid barrier for co-resident blocks (the guide-sanctioned
// inter-workgroup pattern: threadfence + device-scope atomics). `bar` must be
// zeroed before launch; `target` is cumulative (SB, 2*SB, 3*SB, ...).
static __device__ __forceinline__ void grid_sync(int* bar, int target) {
  __syncthreads();
  if (threadIdx.x == 0) {
    __threadfence();                 // publish this block's writes
    atomicAdd(bar, 1);
    while (atomicAdd(bar, 0) < target) {
      __builtin_amdgcn_s_sleep(2);
    }
    __threadfence();                 // acquire other blocks' writes
  }
  __syncthreads();
}

// In-block int64/int32 detection: odd 32-bit words of the first 4KB are the
// hi-halves of src values (< 50000) for int64 -> all zero; for int32 they are
// random src values -> ~surely nonzero.
static __device__ __forceinline__ int detect_is64_block(const void* raw, int* s_tmp) {
  if (threadIdx.x == 0) *s_tmp = 0;
  __syncthreads();
  const unsigned int* w = (const unsigned int*)raw;
  const int nz = (w[1 + 2 * (int)(threadIdx.x & 511)] != 0u) ? 1 : 0;
  if (nz) atomicOr(s_tmp, 1);
  __syncthreads();
  return (*s_tmp == 0) ? 1 : 0;
}

// ---------------------------------------------------------------------------
// ONE kernel for all preprocessing (was 6 dispatches):
//   phase 1: x -> bf16 copy  +  per-block LDS histogram of dst buckets
//   phase 2: per-bucket exclusive scan of block counts -> scatter offsets
//   phase 3: bucketed scatter of packed (dst<<16|src) into ecol
//   phase 4: per-bucket in-place counting sort to CSR order + rowse emit
//            (rowse[v] = csr_start << 9 | deg; col lives bucket-padded in ecol)
__global__ __launch_bounds__(512) void prep_mega(const void* __restrict__ raw,
                                                 const float* __restrict__ xin,
                                                 unsigned short* __restrict__ xb,
                                                 int* __restrict__ blkhist,
                                                 int* __restrict__ offs,
                                                 int* __restrict__ bcount,
                                                 unsigned int* __restrict__ ecol,
                                                 int* __restrict__ rowse,
                                                 int* __restrict__ bar) {
  __shared__ int hist[NBUCK];    // phase 1
  __shared__ int loff[NBUCK];    // phase 3
  __shared__ int lcur[NBUCK];    // phase 3
  __shared__ int dcnt[128];      // phase 4
  __shared__ int noff[128];      // phase 4
  __shared__ int ncur[128];      // phase 4
  __shared__ int s_tmp;

  const int b = blockIdx.x;
  const int tid = (int)threadIdx.x;
  const int is64 = detect_is64_block(raw, &s_tmp);

  // --- phase 1a: x -> bf16 (grid-strided; independent work) ---
  for (int t = b * 512 + tid; t < NNODES * 64 / 4; t += SB * 512) {
    const float4 v = ((const float4*)xin)[t];
    ushort4 o;
    o.x = f2bf(v.x); o.y = f2bf(v.y); o.z = f2bf(v.z); o.w = f2bf(v.w);
    ((ushort4*)xb)[t] = o;
  }
  // --- phase 1b: LDS histogram of this block's edge chunk ---
  for (int i = tid; i < NBUCK; i += 512) hist[i] = 0;
  __syncthreads();
  {
    const int beg = b * CHUNK, end = beg + CHUNK;
    for (int e = beg + tid; e < end; e += 512) {
      const int d = is64 ? (int)((const long long*)raw)[NEDGES + e]
                         : ((const int*)raw)[NEDGES + e];
      atomicAdd(&hist[d >> 7], 1);
    }
  }
  __syncthreads();
  for (int i = tid; i < NBUCK; i += 512) blkhist[i * SB + b] = hist[i];

  grid_sync(bar, SB * 1);

  // --- phase 2: one wave per bucket scans the SB block-counts ---
  {
    const int lane = tid & 63;
    const int bk = b * 8 + (tid >> 6);   // 512 waves total >= NBUCK
    if (bk < NBUCK) {
      const int c = blkhist[bk * SB + lane];
      int s = c;
#pragma unroll
      for (int off = 1; off < 64; off <<= 1) {
        const int u = __shfl_up(s, off, 64);
        if (lane >= off) s += u;
      }
      offs[bk * SB + lane] = bk * BCAP + (s - c);
      if (lane == 63) bcount[bk] = s;
    }
  }

  grid_sync(bar, SB * 2);

  // --- phase 3: bucketed scatter of this block's chunk (LDS cursors only) ---
  for (int i = tid; i < NBUCK; i += 512) {
    loff[i] = offs[i * SB + b];
    lcur[i] = 0;
  }
  __syncthreads();
  {
    const int beg = b * CHUNK, end = beg + CHUNK;
    for (int e = beg + tid; e < end; e += 512) {
      int s, d;
      if (is64) {
        const long long* p = (const long long*)raw;
        s = (int)p[e];
        d = (int)p[NEDGES + e];
      } else {
        const int* p = (const int*)raw;
        s = p[e];
        d = p[NEDGES + e];
      }
      const int bk = d >> 7;
      const unsigned int val = ((unsigned int)d << 16) | (unsigned int)s;
      const int lr = atomicAdd(&lcur[bk], 1);
      ecol[loff[bk] + lr] = val;
    }
  }

  grid_sync(bar, SB * 3);

  // --- phase 4: per-bucket in-place counting sort + rowse emit ---
  for (int bk = b; bk < NBUCK; bk += SB) {
    const int base = bk * 128;
    const int nloc = min(128, NNODES - base);
    const int cnt = bcount[bk];                    // <= BCAP = 3072 = 6*512
    unsigned int* eb = ecol + (size_t)bk * BCAP;
    if (tid < 128) dcnt[tid] = 0;
    __syncthreads();
    // pass A: cache this bucket's edges in registers + per-node counts
    unsigned int vals[6];
    int m = 0;
#pragma unroll
    for (int k = 0; k < 6; ++k) {
      const int e = tid + k * 512;
      if (e < cnt) {
        vals[k] = eb[e];
        atomicAdd(&dcnt[(vals[k] >> 16) & 127u], 1);
        m = k + 1;
      }
    }
    __syncthreads();
    // exclusive scan of dcnt[0..127]
    if (tid < 128) noff[tid] = dcnt[tid];
    __syncthreads();
#pragma unroll
    for (int off = 1; off < 128; off <<= 1) {
      int add = 0;
      if (tid < 128 && tid >= off) add = noff[tid - off];
      __syncthreads();
      if (tid < 128) noff[tid] += add;
      __syncthreads();
    }
    if (tid < 128) {
      const int excl = noff[tid] - dcnt[tid];
      noff[tid] = excl;
      ncur[tid] = 0;
      if (tid < nloc)   // rowse = csr_start (bucket-padded) << 9 | deg
        rowse[base + tid] = ((bk * BCAP + excl) << 9) | dcnt[tid];
    }
    __syncthreads();
    // pass B: in-place place (all reads reg-cached in pass A -> safe)
#pragma unroll
    for (int k = 0; k < 6; ++k) {
      if (k < m) {
        const int loc = (int)((vals[k] >> 16) & 127u);
        eb[noff[loc] + atomicAdd(&ncur[loc], 1)] = vals[k] & 0xFFFFu;
      }
    }
    __syncthreads();
  }
}

// Segment mean, 2 edges per load instruction: lane = (edge-slot, channel-pair).
// rowse[v] = start<<9 | deg (bucket-padded col space). fp32 accumulate.
template <bool FINAL>
__global__ __launch_bounds__(256) void seg_mean_bf(const unsigned int* __restrict__ xb2,
                                                   const int* __restrict__ rowse,
                                                   const unsigned int* __restrict__ col,
                                                   const float* __restrict__ radd,
                                                   float* __restrict__ outbuf) {
  const int lane = (int)(threadIdx.x & 63);
  const int half = lane >> 5;     // edge slot (0: even edges, 1: odd)
  const int c = lane & 31;        // channel pair (chans 2c, 2c+1)
  const int wid = (blockIdx.x * blockDim.x + threadIdx.x) >> 6;
  const int nw = (gridDim.x * blockDim.x) >> 6;
  for (int v = wid; v < NNODES; v += nw) {
    const int se = rowse[v];
    const int b = se >> 9;
    const int e = b + (se & 511);
    float accx = 0.0f, accy = 0.0f;
    int i = b;
    for (; i + 8 <= e; i += 8) {  // 8 edges via 4 dual-edge gathers in flight
      const int s0 = (int)col[i + 0 + half];
      const int s1 = (int)col[i + 2 + half];
      const int s2 = (int)col[i + 4 + half];
      const int s3 = (int)col[i + 6 + half];
      const unsigned int w0 = xb2[(size_t)s0 * 32 + c];
      const unsigned int w1 = xb2[(size_t)s1 * 32 + c];
      const unsigned int w2 = xb2[(size_t)s2 * 32 + c];
      const unsigned int w3 = xb2[(size_t)s3 * 32 + c];
      accx += __uint_as_float(w0 << 16) + __uint_as_float(w1 << 16)
            + __uint_as_float(w2 << 16) + __uint_as_float(w3 << 16);
      accy += __uint_as_float(w0 & 0xFFFF0000u) + __uint_as_float(w1 & 0xFFFF0000u)
            + __uint_as_float(w2 & 0xFFFF0000u) + __uint_as_float(w3 & 0xFFFF0000u);
    }
    for (; i + 2 <= e; i += 2) {  // pair remainder
      const unsigned int w0 = xb2[(size_t)col[i + half] * 32 + c];
      accx += __uint_as_float(w0 << 16);
      accy += __uint_as_float(w0 & 0xFFFF0000u);
    }
    if (i < e && half == 0) {     // odd last edge: slot 0 only
      const unsigned int w0 = xb2[(size_t)col[i] * 32 + c];
      accx += __uint_as_float(w0 << 16);
      accy += __uint_as_float(w0 & 0xFFFF0000u);
    }
    accx += __shfl_xor(accx, 32, 64);
    accy += __shfl_xor(accy, 32, 64);
    if (half == 0) {
      const float inv = 1.0f / fmaxf((float)(se & 511), 1.0f);
      float2 res = make_float2(accx * inv, accy * inv);
      const size_t gi = (size_t)v * 32 + c;
      if (FINAL) {
        const float2 ra = ((const float2*)radd)[gi];
        res.x += ra.x; res.y += ra.y;
      }
      ((float2*)outbuf)[gi] = res;
    }
  }
}

// ---------------------------------------------------------------------------
// Register-tiled fp32 GEMM with v_pk_fma_f32 inner loop:
// C[50000 x 128] = A[50000 x 128] @ W[128 x 128].
// MODE 0 (layer 1): A = [mean1 | x], W = [Wl1 ; Wr1], out = relu(C+b) -> O0[N,128]
// MODE 1 (layer 2): A = h, W = [Wl2 | Wr2],
//                   PB[N,64](bf16) = C[:,0:64] (p); O1[N,64] = C[:,64:128] + b (r)
// ROUND-4 LESSON: do NOT unroll the outer ck loop (VGPR blowout -> scratch
// spill, 2.2 GB/dispatch, 15x slowdown). unroll 1 + 3 blocks/CU bound.
template <int MODE>
__global__ __launch_bounds__(256, 3) void gemm128(const float* __restrict__ A0,
                                                  const float* __restrict__ A1,
                                                  const float* __restrict__ W0,
                                                  const float* __restrict__ W1,
                                                  const float* __restrict__ bias,
                                                  float* __restrict__ O0,
                                                  float* __restrict__ O1,
                                                  unsigned short* __restrict__ PB) {
  constexpr int SAS = 36;  // sA row stride (pad 32->36: rows land on distinct banks)
  __shared__ float sA[64][SAS];
  __shared__ float sW[32][128];
  const int row0 = blockIdx.x * 64;
  const int tid = threadIdx.x;
  const int r0 = (tid >> 4) * 4;
  const int j0 = (tid & 15) * 4;

  float2 accA2[4][2];
  float2 accB2[4][2];
#pragma unroll
  for (int r = 0; r < 4; ++r)
#pragma unroll
    for (int p = 0; p < 2; ++p) {
      accA2[r][p] = make_float2(0.f, 0.f);
      accB2[r][p] = make_float2(0.f, 0.f);
    }

#pragma unroll 1   // keep ONE copy of the body (round-4 lesson)
  for (int ck = 0; ck < 4; ++ck) {
#pragma unroll
    for (int v = 0; v < 2; ++v) {
      const int vid = v * 256 + tid;
      const int rr = vid >> 3;
      const int kq = (vid & 7) * 4;
      const int grow = row0 + rr;
      float4 val = make_float4(0.f, 0.f, 0.f, 0.f);
      if (grow < NNODES) {
        if (MODE == 0) {
          const float* src = (ck < 2) ? A0 : A1;
          const int kk = (ck & 1) * 32 + kq;
          val = *(const float4*)&src[(size_t)grow * 64 + kk];
        } else {
          val = *(const float4*)&A0[(size_t)grow * 128 + ck * 32 + kq];
        }
      }
      *(float4*)&sA[rr][kq] = val;
    }
#pragma unroll
    for (int v = 0; v < 4; ++v) {
      const int vid = v * 256 + tid;
      const int kk = vid >> 5;
      const int jq = (vid & 31) * 4;
      float4 w;
      if (MODE == 0) {
        const float* src = (ck < 2) ? W0 : W1;
        const int krel = (ck & 1) * 32 + kk;
        w = *(const float4*)&src[(size_t)krel * 128 + jq];
      } else {
        const int kg = ck * 32 + kk;
        const float* src = (jq < 64) ? W0 : W1;
        const int jrel = (jq < 64) ? jq : jq - 64;
        w = *(const float4*)&src[(size_t)kg * 64 + jrel];
      }
      *(float4*)&sW[kk][jq] = w;
    }
    __syncthreads();
#pragma unroll
    for (int k4 = 0; k4 < 8; ++k4) {
      float4 a[4];
#pragma unroll
      for (int r = 0; r < 4; ++r) a[r] = *(const float4*)&sA[r0 + r][k4 * 4];
#pragma unroll
      for (int kp = 0; kp < 2; ++kp) {
        const int k_even = k4 * 4 + kp * 2;
        const float4 wlo0 = *(const float4*)&sW[k_even][j0];
        const float4 whi0 = *(const float4*)&sW[k_even][64 + j0];
        const float4 wlo1 = *(const float4*)&sW[k_even + 1][j0];
        const float4 whi1 = *(const float4*)&sW[k_even + 1][64 + j0];
#pragma unroll
        for (int r = 0; r < 4; ++r) {
          const float2 ap = (kp == 0) ? make_float2(a[r].x, a[r].y)
                                      : make_float2(a[r].z, a[r].w);
          pk_fma_lo(accA2[r][0], ap, make_float2(wlo0.x, wlo0.y));
          pk_fma_lo(accA2[r][1], ap, make_float2(wlo0.z, wlo0.w));
          pk_fma_lo(accB2[r][0], ap, make_float2(whi0.x, whi0.y));
          pk_fma_lo(accB2[r][1], ap, make_float2(whi0.z, whi0.w));
          pk_fma_hi(accA2[r][0], ap, make_float2(wlo1.x, wlo1.y));
          pk_fma_hi(accA2[r][1], ap, make_float2(wlo1.z, wlo1.w));
          pk_fma_hi(accB2[r][0], ap, make_float2(whi1.x, whi1.y));
          pk_fma_hi(accB2[r][1], ap, make_float2(whi1.z, whi1.w));
        }
      }
    }
    __syncthreads();
  }

  // --- epilogue ---
  float4 blo = make_float4(0.f, 0.f, 0.f, 0.f);
  float4 bhi;
  if (MODE == 0) {
    blo = *(const float4*)&bias[j0];
    bhi = *(const float4*)&bias[64 + j0];
  } else {
    bhi = *(const float4*)&bias[j0];  // bias applies to r (upper half)
  }
#pragma unroll
  for (int r = 0; r < 4; ++r) {
    const int grow = row0 + r0 + r;
    if (grow >= NNODES) continue;
    float4 lo = make_float4(accA2[r][0].x + blo.x, accA2[r][0].y + blo.y,
                            accA2[r][1].x + blo.z, accA2[r][1].y + blo.w);
    float4 hi = make_float4(accB2[r][0].x + bhi.x, accB2[r][0].y + bhi.y,
                            accB2[r][1].x + bhi.z, accB2[r][1].y + bhi.w);
    if (MODE == 0) {
      lo.x = fmaxf(lo.x, 0.f); lo.y = fmaxf(lo.y, 0.f);
      lo.z = fmaxf(lo.z, 0.f); lo.w = fmaxf(lo.w, 0.f);
      hi.x = fmaxf(hi.x, 0.f); hi.y = fmaxf(hi.y, 0.f);
      hi.z = fmaxf(hi.z, 0.f); hi.w = fmaxf(hi.w, 0.f);
      *(float4*)&O0[(size_t)grow * 128 + j0] = lo;
      *(float4*)&O0[(size_t)grow * 128 + 64 + j0] = hi;
    } else {
      ushort4 ob;
      ob.x = f2bf(lo.x); ob.y = f2bf(lo.y); ob.z = f2bf(lo.z); ob.w = f2bf(lo.w);
      *(ushort4*)&PB[(size_t)grow * 64 + j0] = ob;  // p as bf16 (gather operand)
      *(float4*)&O1[(size_t)grow * 64 + j0] = hi;   // r (+bl2), fp32
    }
  }
}

}  // namespace

extern "C" void kernel_launch(void* const* d_in, const int* in_sizes, int n_in,
                              void* d_out, int out_size, void* d_ws, size_t ws_size,
                              hipStream_t stream) {
  const float* x   = (const float*)d_in[0];
  const void*  ei  = d_in[1];  // edge_index, int32 or int64 (detected in-block)
  const float* Wl1 = (const float*)d_in[2];
  const float* bl1 = (const float*)d_in[3];
  const float* Wr1 = (const float*)d_in[4];
  const float* Wl2 = (const float*)d_in[5];
  const float* bl2 = (const float*)d_in[6];
  const float* Wr2 = (const float*)d_in[7];
  float* out = (float*)d_out;

  // Workspace layout (bytes):
  //   bar     [1]          int32 @ 0          (256)   <- memset to 0 each launch
  //   blkhist [NBUCK*SB]   int32 @ 256        (100,352 padded)
  //   offs    [NBUCK*SB]   int32 @ 100,608    (100,352 padded)
  //   bcount  [NBUCK]      int32 @ 200,960    (2,048)
  //   rowse   [N]          int32 @ 203,008    (200,192 padded)
  //   ecol    [NBUCK*BCAP] u32   @ 403,200    (4,804,608)  packed edges -> sorted col
  //   xb      [N,64]       bf16  @ 5,207,808  (6,400,000)
  //   pb      [N,64]       bf16  @ 11,607,808 (6,400,000)
  //   mean1   [N,64]       f32   @ 18,007,808 (12,800,000)  -- reused as r
  //   h       [N,128]      f32   @ 30,807,808 (25,600,000)
  // total: 56,407,808 bytes.
  char* ws = (char*)d_ws;
  int*            bar     = (int*)(ws + 0);
  int*            blkhist = (int*)(ws + 256);
  int*            offs    = (int*)(ws + 100608);
  int*            bcount  = (int*)(ws + 200960);
  int*            rowse   = (int*)(ws + 203008);
  unsigned int*   ecol    = (unsigned int*)(ws + 403200);
  unsigned short* xb      = (unsigned short*)(ws + 5207808);
  unsigned short* pb      = (unsigned short*)(ws + 11607808);
  float*          mean1   = (float*)(ws + 18007808);
  float*          h       = (float*)(ws + 30807808);
  float*          r       = mean1;  // safe: mean1's last read (gemm128<0>) precedes gemm128<1>'s write

  hipMemsetAsync(bar, 0, 256, stream);  // grid-barrier counter

  // ALL preprocessing in one co-resident kernel (was 6 dispatches):
  // bf16-convert + histogram + scan + scatter + in-place sort + rowse.
  prep_mega<<<SB, 512, 0, stream>>>(ei, x, xb, blkhist, offs, bcount, ecol, rowse, bar);

  constexpr int GEMM_BLOCKS = (NNODES + 63) / 64;  // 782

  // Layer 1: mean-aggregate x (node-parallel dual-edge bf16 gather), then
  // fused linear+relu (packed-fp32 GEMM)
  seg_mean_bf<false><<<12500, 256, 0, stream>>>((const unsigned int*)xb, rowse, ecol,
                                                nullptr, mean1);
  gemm128<0><<<GEMM_BLOCKS, 256, 0, stream>>>(mean1, x, Wl1, Wr1, bl1, h, nullptr, nullptr);

  // Layer 2: project first (mean commutes with linear; p emitted as bf16),
  // then gather + fused add of r
  gemm128<1><<<GEMM_BLOCKS, 256, 0, stream>>>(h, nullptr, Wl2, Wr2, bl2, nullptr, r, pb);
  seg_mean_bf<true><<<12500, 256, 0, stream>>>((const unsigned int*)pb, rowse, ecol,
                                               r, out);
}

// Round 12
// 167.605 us; speedup vs baseline: 1.1468x; 1.1468x over previous
//
#include <hip/hip_runtime.h>

namespace {

constexpr int NNODES = 50000;
constexpr int NEDGES = 800000;
constexpr int NBUCK  = (NNODES + 127) / 128;  // 391 buckets of 128 dst nodes
constexpr int BCAP   = 3072;                  // bucket capacity: mean 2048, ~22 sigma slack
constexpr int SB     = 64;                    // scatter/hist blocks
constexpr int CHUNK  = NEDGES / SB;           // 12500 edges per block (exact)
constexpr int CONVB  = 1024;                  // bf16-convert blocks (in histconv)

// ROUND-6: per-address global atomic ~140ns serialized -> never >1K ops/address.
// ROUND-7: aggregation must be node-parallel (50K waves), never bucket-parallel.
// ROUND-9: seg_mean is latency/issue-bound, not byte-bound.
// ROUND-11: grid-barrier mega-fusion caps every phase at the launch grid
// (64 blocks = 25% of CUs, 5.3% occupancy, REGRESSED). Fuse only where no
// cross-block dependency exists; keep each phase's natural grid.

static __device__ __forceinline__ unsigned short f2bf(float f) {
  unsigned u = __float_as_uint(f);
  u += 0x7FFFu + ((u >> 16) & 1u);   // round-to-nearest-even
  return (unsigned short)(u >> 16);
}

// v_pk_fma_f32 with op_sel broadcast of one half of src0 (2 FMA/lane/cycle).
static __device__ __forceinline__ void pk_fma_lo(float2& d, const float2 a, const float2 b) {
  asm("v_pk_fma_f32 %0, %1, %2, %0 op_sel:[0,0,0] op_sel_hi:[0,1,1]"
      : "+v"(d) : "v"(a), "v"(b));
}
static __device__ __forceinline__ void pk_fma_hi(float2& d, const float2 a, const float2 b) {
  asm("v_pk_fma_f32 %0, %1, %2, %0 op_sel:[1,0,0] op_sel_hi:[1,1,1]"
      : "+v"(d) : "v"(a), "v"(b));
}

// In-block int64/int32 detection: odd 32-bit words of the first 4KB are the
// hi-halves of src values (< 50000) for int64 -> all zero; for int32 they are
// random values -> ~surely nonzero.
static __device__ __forceinline__ int detect_is64_block(const void* raw, int* s_tmp) {
  if (threadIdx.x == 0) *s_tmp = 0;
  __syncthreads();
  const unsigned int* w = (const unsigned int*)raw;
  const int nz = (w[1 + 2 * (int)(threadIdx.x & 511)] != 0u) ? 1 : 0;
  if (nz) atomicOr(s_tmp, 1);
  __syncthreads();
  return (*s_tmp == 0) ? 1 : 0;
}

// ---------------------------------------------------------------------------
// Fused launch of two INDEPENDENT jobs (no barrier needed):
//   blocks 0..SB-1      : per-block LDS histogram of dst buckets
//   blocks SB..SB+CONVB : x -> bf16 convert (grid-strided)
__global__ __launch_bounds__(512) void histconv(const void* __restrict__ raw,
                                                const float* __restrict__ xin,
                                                unsigned short* __restrict__ xb,
                                                int* __restrict__ blkhist) {
  const int tid = (int)threadIdx.x;
  if (blockIdx.x >= SB) {
    const int b = blockIdx.x - SB;
    for (int t = b * 512 + tid; t < NNODES * 64 / 4; t += CONVB * 512) {
      const float4 v = ((const float4*)xin)[t];
      ushort4 o;
      o.x = f2bf(v.x); o.y = f2bf(v.y); o.z = f2bf(v.z); o.w = f2bf(v.w);
      ((ushort4*)xb)[t] = o;
    }
    return;
  }
  __shared__ int hist[NBUCK];
  __shared__ int s_tmp;
  const int is64 = detect_is64_block(raw, &s_tmp);
  for (int i = tid; i < NBUCK; i += 512) hist[i] = 0;
  __syncthreads();
  const int b = blockIdx.x;
  const int beg = b * CHUNK, end = beg + CHUNK;
  for (int e = beg + tid; e < end; e += 512) {
    const int d = is64 ? (int)((const long long*)raw)[NEDGES + e]
                       : ((const int*)raw)[NEDGES + e];
    atomicAdd(&hist[d >> 7], 1);
  }
  __syncthreads();
  for (int i = tid; i < NBUCK; i += 512) blkhist[i * SB + b] = hist[i];
}

// Bucketed scatter; each block computes ITS OWN bucket offsets from blkhist
// (<= 63 independent L2-resident adds per bucket -> pipelined, ~us), killing
// the separate col_scan dispatch. LDS cursors only, zero global atomics.
__global__ __launch_bounds__(512) void scatter_pass(const void* __restrict__ raw,
                                                    const int* __restrict__ blkhist,
                                                    unsigned int* __restrict__ ecol) {
  __shared__ int loff[NBUCK];
  __shared__ int lcur[NBUCK];
  __shared__ int s_tmp;
  const int is64 = detect_is64_block(raw, &s_tmp);
  const int b = blockIdx.x;
  const int tid = (int)threadIdx.x;
  for (int bk = tid; bk < NBUCK; bk += 512) {
    int s = 0;
    for (int bb = 0; bb < b; ++bb) s += blkhist[bk * SB + bb];
    loff[bk] = bk * BCAP + s;
    lcur[bk] = 0;
  }
  __syncthreads();
  const int beg = b * CHUNK, end = beg + CHUNK;
  for (int e = beg + tid; e < end; e += 512) {
    int s, d;
    if (is64) {
      const long long* p = (const long long*)raw;
      s = (int)p[e];
      d = (int)p[NEDGES + e];
    } else {
      const int* p = (const int*)raw;
      s = p[e];
      d = p[NEDGES + e];
    }
    const int bk = d >> 7;
    const unsigned int val = ((unsigned int)d << 16) | (unsigned int)s;
    const int lr = atomicAdd(&lcur[bk], 1);
    ecol[loff[bk] + lr] = val;
  }
}

// One block per bucket: in-place counting sort of the bucket's packed edges
// to CSR order (src values only), computing the bucket count from blkhist
// itself; emits packed rowse[v] = csr_start(bucket-padded) << 9 | deg.
__global__ __launch_bounds__(256) void csr_emit(const int* __restrict__ blkhist,
                                                unsigned int* __restrict__ ecol,
                                                int* __restrict__ rowse) {
  const int bk = blockIdx.x;
  const int base = bk * 128;
  const int nloc = min(128, NNODES - base);
  const int tid = (int)threadIdx.x;
  unsigned int* eb = ecol + (size_t)bk * BCAP;

  __shared__ int dcnt[128];
  __shared__ int noff[128];
  __shared__ int ncur[128];
  __shared__ int s_cnt;
  // bucket count = sum of this bucket's 64 block-counts (wave 0)
  if (tid < 64) {
    int c = blkhist[bk * SB + tid];
#pragma unroll
    for (int off = 32; off; off >>= 1) c += __shfl_down(c, off, 64);
    if (tid == 0) s_cnt = c;
  }
  if (tid < 128) dcnt[tid] = 0;
  __syncthreads();
  const int cnt = s_cnt;               // <= BCAP = 3072 = 12*256

  // pass A: cache edges in registers + per-node counts
  unsigned int vals[12];
  int m = 0;
#pragma unroll
  for (int k = 0; k < 12; ++k) {
    const int e = tid + k * 256;
    if (e < cnt) {
      vals[k] = eb[e];
      atomicAdd(&dcnt[(vals[k] >> 16) & 127u], 1);
      m = k + 1;
    }
  }
  __syncthreads();

  // exclusive scan of dcnt[0..127]
  if (tid < 128) noff[tid] = dcnt[tid];
  __syncthreads();
#pragma unroll
  for (int off = 1; off < 128; off <<= 1) {
    int add = 0;
    if (tid < 128 && tid >= off) add = noff[tid - off];
    __syncthreads();
    if (tid < 128) noff[tid] += add;
    __syncthreads();
  }
  if (tid < 128) {
    const int excl = noff[tid] - dcnt[tid];
    noff[tid] = excl;
    ncur[tid] = 0;
    if (tid < nloc)
      rowse[base + tid] = ((bk * BCAP + excl) << 9) | dcnt[tid];
  }
  __syncthreads();

  // pass B: in-place place (all reads were reg-cached in pass A -> safe)
#pragma unroll
  for (int k = 0; k < 12; ++k) {
    if (k < m) {
      const int loc = (int)((vals[k] >> 16) & 127u);
      eb[noff[loc] + atomicAdd(&ncur[loc], 1)] = vals[k] & 0xFFFFu;
    }
  }
}

// Segment mean, 2 edges per load instruction: lane = (edge-slot, channel-pair).
// rowse[v] = start<<9 | deg (bucket-padded col space). fp32 accumulate.
template <bool FINAL>
__global__ __launch_bounds__(256) void seg_mean_bf(const unsigned int* __restrict__ xb2,
                                                   const int* __restrict__ rowse,
                                                   const unsigned int* __restrict__ col,
                                                   const float* __restrict__ radd,
                                                   float* __restrict__ outbuf) {
  const int lane = (int)(threadIdx.x & 63);
  const int half = lane >> 5;     // edge slot (0: even edges, 1: odd)
  const int c = lane & 31;        // channel pair (chans 2c, 2c+1)
  const int wid = (blockIdx.x * blockDim.x + threadIdx.x) >> 6;
  const int nw = (gridDim.x * blockDim.x) >> 6;
  for (int v = wid; v < NNODES; v += nw) {
    const int se = rowse[v];
    const int b = se >> 9;
    const int e = b + (se & 511);
    float accx = 0.0f, accy = 0.0f;
    int i = b;
    for (; i + 8 <= e; i += 8) {  // 8 edges via 4 dual-edge gathers in flight
      const int s0 = (int)col[i + 0 + half];
      const int s1 = (int)col[i + 2 + half];
      const int s2 = (int)col[i + 4 + half];
      const int s3 = (int)col[i + 6 + half];
      const unsigned int w0 = xb2[(size_t)s0 * 32 + c];
      const unsigned int w1 = xb2[(size_t)s1 * 32 + c];
      const unsigned int w2 = xb2[(size_t)s2 * 32 + c];
      const unsigned int w3 = xb2[(size_t)s3 * 32 + c];
      accx += __uint_as_float(w0 << 16) + __uint_as_float(w1 << 16)
            + __uint_as_float(w2 << 16) + __uint_as_float(w3 << 16);
      accy += __uint_as_float(w0 & 0xFFFF0000u) + __uint_as_float(w1 & 0xFFFF0000u)
            + __uint_as_float(w2 & 0xFFFF0000u) + __uint_as_float(w3 & 0xFFFF0000u);
    }
    for (; i + 2 <= e; i += 2) {  // pair remainder
      const unsigned int w0 = xb2[(size_t)col[i + half] * 32 + c];
      accx += __uint_as_float(w0 << 16);
      accy += __uint_as_float(w0 & 0xFFFF0000u);
    }
    if (i < e && half == 0) {     // odd last edge: slot 0 only
      const unsigned int w0 = xb2[(size_t)col[i] * 32 + c];
      accx += __uint_as_float(w0 << 16);
      accy += __uint_as_float(w0 & 0xFFFF0000u);
    }
    accx += __shfl_xor(accx, 32, 64);
    accy += __shfl_xor(accy, 32, 64);
    if (half == 0) {
      const float inv = 1.0f / fmaxf((float)(se & 511), 1.0f);
      float2 res = make_float2(accx * inv, accy * inv);
      const size_t gi = (size_t)v * 32 + c;
      if (FINAL) {
        const float2 ra = ((const float2*)radd)[gi];
        res.x += ra.x; res.y += ra.y;
      }
      ((float2*)outbuf)[gi] = res;
    }
  }
}

// ---------------------------------------------------------------------------
// FUSED two-layer GEMM (same-row dependency -> no barrier needed):
// per block of 64 rows:
//   GEMM1: h = relu([mean1|x] @ [Wl1;Wr1] + bl1) -> kept in LDS (sH)
//   GEMM2: [p|r] = h @ [Wl2|Wr2] (+bl2 on r); p -> bf16 PB, r -> f32 R.
// Deletes the 51MB h round-trip and one dispatch.
// ROUND-4 LESSON: do NOT unroll the outer ck loops (VGPR blowout -> spill).
__global__ __launch_bounds__(256, 2) void gemm_fused(const float* __restrict__ MEAN1,
                                                     const float* __restrict__ X,
                                                     const float* __restrict__ Wl1,
                                                     const float* __restrict__ Wr1,
                                                     const float* __restrict__ bl1,
                                                     const float* __restrict__ Wl2,
                                                     const float* __restrict__ Wr2,
                                                     const float* __restrict__ bl2,
                                                     unsigned short* __restrict__ PB,
                                                     float* __restrict__ R) {
  constexpr int SAS = 36;   // sA row stride (pad: rowgrp stride 16 banks -> 2-way, free)
  constexpr int SHS = 132;  // sH row stride (same property)
  __shared__ float sA[64][SAS];
  __shared__ float sW[32][128];
  __shared__ float sH[64][SHS];   // 9.2 + 16.4 + 33.8 = 59.4 KB LDS -> 2 blocks/CU
  const int row0 = blockIdx.x * 64;
  const int tid = threadIdx.x;
  const int r0 = (tid >> 4) * 4;
  const int j0 = (tid & 15) * 4;

  float2 accA2[4][2];
  float2 accB2[4][2];
#pragma unroll
  for (int r = 0; r < 4; ++r)
#pragma unroll
    for (int p = 0; p < 2; ++p) {
      accA2[r][p] = make_float2(0.f, 0.f);
      accB2[r][p] = make_float2(0.f, 0.f);
    }

  // ---------------- GEMM1: A = [mean1 | x], W = [Wl1 ; Wr1] ----------------
#pragma unroll 1
  for (int ck = 0; ck < 4; ++ck) {
#pragma unroll
    for (int v = 0; v < 2; ++v) {
      const int vid = v * 256 + tid;
      const int rr = vid >> 3;
      const int kq = (vid & 7) * 4;
      const int grow = row0 + rr;
      float4 val = make_float4(0.f, 0.f, 0.f, 0.f);
      if (grow < NNODES) {
        const float* src = (ck < 2) ? MEAN1 : X;
        const int kk = (ck & 1) * 32 + kq;
        val = *(const float4*)&src[(size_t)grow * 64 + kk];
      }
      *(float4*)&sA[rr][kq] = val;
    }
#pragma unroll
    for (int v = 0; v < 4; ++v) {
      const int vid = v * 256 + tid;
      const int kk = vid >> 5;
      const int jq = (vid & 31) * 4;
      const float* src = (ck < 2) ? Wl1 : Wr1;
      const int krel = (ck & 1) * 32 + kk;
      *(float4*)&sW[kk][jq] = *(const float4*)&src[(size_t)krel * 128 + jq];
    }
    __syncthreads();
#pragma unroll
    for (int k4 = 0; k4 < 8; ++k4) {
      float4 a[4];
#pragma unroll
      for (int r = 0; r < 4; ++r) a[r] = *(const float4*)&sA[r0 + r][k4 * 4];
#pragma unroll
      for (int kp = 0; kp < 2; ++kp) {
        const int k_even = k4 * 4 + kp * 2;
        const float4 wlo0 = *(const float4*)&sW[k_even][j0];
        const float4 whi0 = *(const float4*)&sW[k_even][64 + j0];
        const float4 wlo1 = *(const float4*)&sW[k_even + 1][j0];
        const float4 whi1 = *(const float4*)&sW[k_even + 1][64 + j0];
#pragma unroll
        for (int r = 0; r < 4; ++r) {
          const float2 ap = (kp == 0) ? make_float2(a[r].x, a[r].y)
                                      : make_float2(a[r].z, a[r].w);
          pk_fma_lo(accA2[r][0], ap, make_float2(wlo0.x, wlo0.y));
          pk_fma_lo(accA2[r][1], ap, make_float2(wlo0.z, wlo0.w));
          pk_fma_lo(accB2[r][0], ap, make_float2(whi0.x, whi0.y));
          pk_fma_lo(accB2[r][1], ap, make_float2(whi0.z, whi0.w));
          pk_fma_hi(accA2[r][0], ap, make_float2(wlo1.x, wlo1.y));
          pk_fma_hi(accA2[r][1], ap, make_float2(wlo1.z, wlo1.w));
          pk_fma_hi(accB2[r][0], ap, make_float2(whi1.x, whi1.y));
          pk_fma_hi(accB2[r][1], ap, make_float2(whi1.z, whi1.w));
        }
      }
    }
    __syncthreads();
  }

  // epilogue1: h = relu(acc + bl1) -> LDS
  {
    const float4 blo = *(const float4*)&bl1[j0];
    const float4 bhi = *(const float4*)&bl1[64 + j0];
#pragma unroll
    for (int r = 0; r < 4; ++r) {
      float4 lo = make_float4(fmaxf(accA2[r][0].x + blo.x, 0.f),
                              fmaxf(accA2[r][0].y + blo.y, 0.f),
                              fmaxf(accA2[r][1].x + blo.z, 0.f),
                              fmaxf(accA2[r][1].y + blo.w, 0.f));
      float4 hi = make_float4(fmaxf(accB2[r][0].x + bhi.x, 0.f),
                              fmaxf(accB2[r][0].y + bhi.y, 0.f),
                              fmaxf(accB2[r][1].x + bhi.z, 0.f),
                              fmaxf(accB2[r][1].y + bhi.w, 0.f));
      *(float4*)&sH[r0 + r][j0] = lo;
      *(float4*)&sH[r0 + r][64 + j0] = hi;
      accA2[r][0] = make_float2(0.f, 0.f); accA2[r][1] = make_float2(0.f, 0.f);
      accB2[r][0] = make_float2(0.f, 0.f); accB2[r][1] = make_float2(0.f, 0.f);
    }
  }
  __syncthreads();

  // ---------------- GEMM2: A = sH (in LDS), W = [Wl2 | Wr2] ----------------
#pragma unroll 1
  for (int ck = 0; ck < 4; ++ck) {
#pragma unroll
    for (int v = 0; v < 4; ++v) {
      const int vid = v * 256 + tid;
      const int kk = vid >> 5;
      const int jq = (vid & 31) * 4;
      const int kg = ck * 32 + kk;
      const float* src = (jq < 64) ? Wl2 : Wr2;
      const int jrel = (jq < 64) ? jq : jq - 64;
      *(float4*)&sW[kk][jq] = *(const float4*)&src[(size_t)kg * 64 + jrel];
    }
    __syncthreads();
#pragma unroll
    for (int k4 = 0; k4 < 8; ++k4) {
      float4 a[4];
#pragma unroll
      for (int r = 0; r < 4; ++r) a[r] = *(const float4*)&sH[r0 + r][ck * 32 + k4 * 4];
#pragma unroll
      for (int kp = 0; kp < 2; ++kp) {
        const int k_even = k4 * 4 + kp * 2;
        const float4 wlo0 = *(const float4*)&sW[k_even][j0];
        const float4 whi0 = *(const float4*)&sW[k_even][64 + j0];
        const float4 wlo1 = *(const float4*)&sW[k_even + 1][j0];
        const float4 whi1 = *(const float4*)&sW[k_even + 1][64 + j0];
#pragma unroll
        for (int r = 0; r < 4; ++r) {
          const float2 ap = (kp == 0) ? make_float2(a[r].x, a[r].y)
                                      : make_float2(a[r].z, a[r].w);
          pk_fma_lo(accA2[r][0], ap, make_float2(wlo0.x, wlo0.y));
          pk_fma_lo(accA2[r][1], ap, make_float2(wlo0.z, wlo0.w));
          pk_fma_lo(accB2[r][0], ap, make_float2(whi0.x, whi0.y));
          pk_fma_lo(accB2[r][1], ap, make_float2(whi0.z, whi0.w));
          pk_fma_hi(accA2[r][0], ap, make_float2(wlo1.x, wlo1.y));
          pk_fma_hi(accA2[r][1], ap, make_float2(wlo1.z, wlo1.w));
          pk_fma_hi(accB2[r][0], ap, make_float2(whi1.x, whi1.y));
          pk_fma_hi(accB2[r][1], ap, make_float2(whi1.z, whi1.w));
        }
      }
    }
    __syncthreads();
  }

  // epilogue2: p (cols 0..63, no bias) -> bf16 PB; r (cols 64..127 + bl2) -> f32 R
  {
    const float4 bhi = *(const float4*)&bl2[j0];
#pragma unroll
    for (int r = 0; r < 4; ++r) {
      const int grow = row0 + r0 + r;
      if (grow >= NNODES) continue;
      ushort4 ob;
      ob.x = f2bf(accA2[r][0].x); ob.y = f2bf(accA2[r][0].y);
      ob.z = f2bf(accA2[r][1].x); ob.w = f2bf(accA2[r][1].y);
      *(ushort4*)&PB[(size_t)grow * 64 + j0] = ob;
      float4 hi = make_float4(accB2[r][0].x + bhi.x, accB2[r][0].y + bhi.y,
                              accB2[r][1].x + bhi.z, accB2[r][1].y + bhi.w);
      *(float4*)&R[(size_t)grow * 64 + j0] = hi;
    }
  }
}

}  // namespace

extern "C" void kernel_launch(void* const* d_in, const int* in_sizes, int n_in,
                              void* d_out, int out_size, void* d_ws, size_t ws_size,
                              hipStream_t stream) {
  const float* x   = (const float*)d_in[0];
  const void*  ei  = d_in[1];  // edge_index, int32 or int64 (detected in-block)
  const float* Wl1 = (const float*)d_in[2];
  const float* bl1 = (const float*)d_in[3];
  const float* Wr1 = (const float*)d_in[4];
  const float* Wl2 = (const float*)d_in[5];
  const float* bl2 = (const float*)d_in[6];
  const float* Wr2 = (const float*)d_in[7];
  float* out = (float*)d_out;

  // Workspace layout (bytes):
  //   blkhist [NBUCK*SB]   int32 @ 0          (100,352 padded)
  //   rowse   [N]          int32 @ 100,352    (200,704 padded)
  //   ecol    [NBUCK*BCAP] u32   @ 301,056    (4,804,608)  packed edges -> sorted src
  //   xb      [N,64]       bf16  @ 5,105,664  (6,400,000)
  //   pb      [N,64]       bf16  @ 11,505,664 (6,400,000)
  //   mean1   [N,64]       f32   @ 17,905,664 (12,800,000)  -- reused as r
  // total: 30,705,664 bytes. No memsets: every buffer fully written before read.
  char* ws = (char*)d_ws;
  int*            blkhist = (int*)(ws + 0);
  int*            rowse   = (int*)(ws + 100352);
  unsigned int*   ecol    = (unsigned int*)(ws + 301056);
  unsigned short* xb      = (unsigned short*)(ws + 5105664);
  unsigned short* pb      = (unsigned short*)(ws + 11505664);
  float*          mean1   = (float*)(ws + 17905664);
  float*          r       = mean1;  // safe: gemm_fused reads mean1[row] (GEMM1 staging)
                                    // strictly before writing r[row] (epilogue2), per block

  // 6 dispatches total (was 10): no barriers, each phase keeps its natural grid.
  histconv<<<SB + CONVB, 512, 0, stream>>>(ei, x, xb, blkhist);
  scatter_pass<<<SB, 512, 0, stream>>>(ei, blkhist, ecol);
  csr_emit<<<NBUCK, 256, 0, stream>>>(blkhist, ecol, rowse);

  constexpr int GEMM_BLOCKS = (NNODES + 63) / 64;  // 782

  seg_mean_bf<false><<<12500, 256, 0, stream>>>((const unsigned int*)xb, rowse, ecol,
                                                nullptr, mean1);
  gemm_fused<<<GEMM_BLOCKS, 256, 0, stream>>>(mean1, x, Wl1, Wr1, bl1,
                                              Wl2, Wr2, bl2, pb, r);
  seg_mean_bf<true><<<12500, 256, 0, stream>>>((const unsigned int*)pb, rowse, ecol,
                                               r, out);
}

// Round 13
// 159.081 us; speedup vs baseline: 1.2083x; 1.0536x over previous
//
#include <hip/hip_runtime.h>

namespace {

constexpr int NNODES = 50000;
constexpr int NEDGES = 800000;
constexpr int NBUCK  = (NNODES + 127) / 128;  // 391 buckets of 128 dst nodes
constexpr int BCAP   = 3072;                  // bucket capacity: mean 2048, ~22 sigma slack
constexpr int SB     = 64;                    // scatter/hist blocks
constexpr int CHUNK  = NEDGES / SB;           // 12500 edges per block (exact)
constexpr int CONVB  = 1024;                  // bf16-convert blocks (in histconv)

// ROUND-6: per-address global atomic ~140ns serialized -> never >1K ops/address.
// ROUND-7: aggregation must be node-parallel (50K waves), never bucket-parallel.
// ROUND-9: seg_mean is latency/issue-bound, not byte-bound.
// ROUND-11: grid-barrier mega-fusion caps every phase at the launch grid -> REGRESSED.
// ROUND-12: fusing the two GEMMs into one block (59KB LDS -> 2 blocks/CU, double
// barrier chain) starved the pipeline: 86us vs ~40us separate. Keep GEMMs split;
// keep round-12's preprocessing fusion (histconv || convert, self-service offsets).

static __device__ __forceinline__ unsigned short f2bf(float f) {
  unsigned u = __float_as_uint(f);
  u += 0x7FFFu + ((u >> 16) & 1u);   // round-to-nearest-even
  return (unsigned short)(u >> 16);
}

// v_pk_fma_f32 with op_sel broadcast of one half of src0 (2 FMA/lane/cycle).
static __device__ __forceinline__ void pk_fma_lo(float2& d, const float2 a, const float2 b) {
  asm("v_pk_fma_f32 %0, %1, %2, %0 op_sel:[0,0,0] op_sel_hi:[0,1,1]"
      : "+v"(d) : "v"(a), "v"(b));
}
static __device__ __forceinline__ void pk_fma_hi(float2& d, const float2 a, const float2 b) {
  asm("v_pk_fma_f32 %0, %1, %2, %0 op_sel:[1,0,0] op_sel_hi:[1,1,1]"
      : "+v"(d) : "v"(a), "v"(b));
}

// In-block int64/int32 detection: odd 32-bit words of the first 4KB are the
// hi-halves of src values (< 50000) for int64 -> all zero; for int32 they are
// random values -> ~surely nonzero.
static __device__ __forceinline__ int detect_is64_block(const void* raw, int* s_tmp) {
  if (threadIdx.x == 0) *s_tmp = 0;
  __syncthreads();
  const unsigned int* w = (const unsigned int*)raw;
  const int nz = (w[1 + 2 * (int)(threadIdx.x & 511)] != 0u) ? 1 : 0;
  if (nz) atomicOr(s_tmp, 1);
  __syncthreads();
  return (*s_tmp == 0) ? 1 : 0;
}

// ---------------------------------------------------------------------------
// Fused launch of two INDEPENDENT jobs (no barrier needed):
//   blocks 0..SB-1      : per-block LDS histogram of dst buckets
//   blocks SB..SB+CONVB : x -> bf16 convert (grid-strided)
__global__ __launch_bounds__(512) void histconv(const void* __restrict__ raw,
                                                const float* __restrict__ xin,
                                                unsigned short* __restrict__ xb,
                                                int* __restrict__ blkhist) {
  const int tid = (int)threadIdx.x;
  if (blockIdx.x >= SB) {
    const int b = blockIdx.x - SB;
    for (int t = b * 512 + tid; t < NNODES * 64 / 4; t += CONVB * 512) {
      const float4 v = ((const float4*)xin)[t];
      ushort4 o;
      o.x = f2bf(v.x); o.y = f2bf(v.y); o.z = f2bf(v.z); o.w = f2bf(v.w);
      ((ushort4*)xb)[t] = o;
    }
    return;
  }
  __shared__ int hist[NBUCK];
  __shared__ int s_tmp;
  const int is64 = detect_is64_block(raw, &s_tmp);
  for (int i = tid; i < NBUCK; i += 512) hist[i] = 0;
  __syncthreads();
  const int b = blockIdx.x;
  const int beg = b * CHUNK, end = beg + CHUNK;
  for (int e = beg + tid; e < end; e += 512) {
    const int d = is64 ? (int)((const long long*)raw)[NEDGES + e]
                       : ((const int*)raw)[NEDGES + e];
    atomicAdd(&hist[d >> 7], 1);
  }
  __syncthreads();
  for (int i = tid; i < NBUCK; i += 512) blkhist[i * SB + b] = hist[i];
}

// Bucketed scatter; each block computes ITS OWN bucket offsets from blkhist
// (<= 63 independent L2-resident adds per bucket -> pipelined), killing the
// separate col_scan dispatch. LDS cursors only, zero global atomics.
__global__ __launch_bounds__(512) void scatter_pass(const void* __restrict__ raw,
                                                    const int* __restrict__ blkhist,
                                                    unsigned int* __restrict__ ecol) {
  __shared__ int loff[NBUCK];
  __shared__ int lcur[NBUCK];
  __shared__ int s_tmp;
  const int is64 = detect_is64_block(raw, &s_tmp);
  const int b = blockIdx.x;
  const int tid = (int)threadIdx.x;
  for (int bk = tid; bk < NBUCK; bk += 512) {
    int s = 0;
    for (int bb = 0; bb < b; ++bb) s += blkhist[bk * SB + bb];
    loff[bk] = bk * BCAP + s;
    lcur[bk] = 0;
  }
  __syncthreads();
  const int beg = b * CHUNK, end = beg + CHUNK;
  for (int e = beg + tid; e < end; e += 512) {
    int s, d;
    if (is64) {
      const long long* p = (const long long*)raw;
      s = (int)p[e];
      d = (int)p[NEDGES + e];
    } else {
      const int* p = (const int*)raw;
      s = p[e];
      d = p[NEDGES + e];
    }
    const int bk = d >> 7;
    const unsigned int val = ((unsigned int)d << 16) | (unsigned int)s;
    const int lr = atomicAdd(&lcur[bk], 1);
    ecol[loff[bk] + lr] = val;
  }
}

// One block per bucket: in-place counting sort of the bucket's packed edges
// to CSR order (src values only), computing the bucket count from blkhist;
// emits packed rowse[v] = csr_start(bucket-padded) << 9 | deg.
__global__ __launch_bounds__(256) void csr_emit(const int* __restrict__ blkhist,
                                                unsigned int* __restrict__ ecol,
                                                int* __restrict__ rowse) {
  const int bk = blockIdx.x;
  const int base = bk * 128;
  const int nloc = min(128, NNODES - base);
  const int tid = (int)threadIdx.x;
  unsigned int* eb = ecol + (size_t)bk * BCAP;

  __shared__ int dcnt[128];
  __shared__ int noff[128];
  __shared__ int ncur[128];
  __shared__ int s_cnt;
  // bucket count = sum of this bucket's 64 block-counts (wave 0)
  if (tid < 64) {
    int c = blkhist[bk * SB + tid];
#pragma unroll
    for (int off = 32; off; off >>= 1) c += __shfl_down(c, off, 64);
    if (tid == 0) s_cnt = c;
  }
  if (tid < 128) dcnt[tid] = 0;
  __syncthreads();
  const int cnt = s_cnt;               // <= BCAP = 3072 = 12*256

  // pass A: cache edges in registers + per-node counts
  unsigned int vals[12];
  int m = 0;
#pragma unroll
  for (int k = 0; k < 12; ++k) {
    const int e = tid + k * 256;
    if (e < cnt) {
      vals[k] = eb[e];
      atomicAdd(&dcnt[(vals[k] >> 16) & 127u], 1);
      m = k + 1;
    }
  }
  __syncthreads();

  // exclusive scan of dcnt[0..127]
  if (tid < 128) noff[tid] = dcnt[tid];
  __syncthreads();
#pragma unroll
  for (int off = 1; off < 128; off <<= 1) {
    int add = 0;
    if (tid < 128 && tid >= off) add = noff[tid - off];
    __syncthreads();
    if (tid < 128) noff[tid] += add;
    __syncthreads();
  }
  if (tid < 128) {
    const int excl = noff[tid] - dcnt[tid];
    noff[tid] = excl;
    ncur[tid] = 0;
    if (tid < nloc)
      rowse[base + tid] = ((bk * BCAP + excl) << 9) | dcnt[tid];
  }
  __syncthreads();

  // pass B: in-place place (all reads were reg-cached in pass A -> safe)
#pragma unroll
  for (int k = 0; k < 12; ++k) {
    if (k < m) {
      const int loc = (int)((vals[k] >> 16) & 127u);
      eb[noff[loc] + atomicAdd(&ncur[loc], 1)] = vals[k] & 0xFFFFu;
    }
  }
}

// Segment mean, 2 edges per load instruction: lane = (edge-slot, channel-pair).
// rowse[v] = start<<9 | deg (bucket-padded col space). fp32 accumulate.
template <bool FINAL>
__global__ __launch_bounds__(256) void seg_mean_bf(const unsigned int* __restrict__ xb2,
                                                   const int* __restrict__ rowse,
                                                   const unsigned int* __restrict__ col,
                                                   const float* __restrict__ radd,
                                                   float* __restrict__ outbuf) {
  const int lane = (int)(threadIdx.x & 63);
  const int half = lane >> 5;     // edge slot (0: even edges, 1: odd)
  const int c = lane & 31;        // channel pair (chans 2c, 2c+1)
  const int wid = (blockIdx.x * blockDim.x + threadIdx.x) >> 6;
  const int nw = (gridDim.x * blockDim.x) >> 6;
  for (int v = wid; v < NNODES; v += nw) {
    const int se = rowse[v];
    const int b = se >> 9;
    const int e = b + (se & 511);
    float accx = 0.0f, accy = 0.0f;
    int i = b;
    for (; i + 8 <= e; i += 8) {  // 8 edges via 4 dual-edge gathers in flight
      const int s0 = (int)col[i + 0 + half];
      const int s1 = (int)col[i + 2 + half];
      const int s2 = (int)col[i + 4 + half];
      const int s3 = (int)col[i + 6 + half];
      const unsigned int w0 = xb2[(size_t)s0 * 32 + c];
      const unsigned int w1 = xb2[(size_t)s1 * 32 + c];
      const unsigned int w2 = xb2[(size_t)s2 * 32 + c];
      const unsigned int w3 = xb2[(size_t)s3 * 32 + c];
      accx += __uint_as_float(w0 << 16) + __uint_as_float(w1 << 16)
            + __uint_as_float(w2 << 16) + __uint_as_float(w3 << 16);
      accy += __uint_as_float(w0 & 0xFFFF0000u) + __uint_as_float(w1 & 0xFFFF0000u)
            + __uint_as_float(w2 & 0xFFFF0000u) + __uint_as_float(w3 & 0xFFFF0000u);
    }
    for (; i + 2 <= e; i += 2) {  // pair remainder
      const unsigned int w0 = xb2[(size_t)col[i + half] * 32 + c];
      accx += __uint_as_float(w0 << 16);
      accy += __uint_as_float(w0 & 0xFFFF0000u);
    }
    if (i < e && half == 0) {     // odd last edge: slot 0 only
      const unsigned int w0 = xb2[(size_t)col[i] * 32 + c];
      accx += __uint_as_float(w0 << 16);
      accy += __uint_as_float(w0 & 0xFFFF0000u);
    }
    accx += __shfl_xor(accx, 32, 64);
    accy += __shfl_xor(accy, 32, 64);
    if (half == 0) {
      const float inv = 1.0f / fmaxf((float)(se & 511), 1.0f);
      float2 res = make_float2(accx * inv, accy * inv);
      const size_t gi = (size_t)v * 32 + c;
      if (FINAL) {
        const float2 ra = ((const float2*)radd)[gi];
        res.x += ra.x; res.y += ra.y;
      }
      ((float2*)outbuf)[gi] = res;
    }
  }
}

// ---------------------------------------------------------------------------
// Register-tiled fp32 GEMM with v_pk_fma_f32 inner loop (round-10 version:
// 25.6KB LDS, 3 blocks/CU -- do NOT fuse the two layers, round-12 lesson):
// C[50000 x 128] = A[50000 x 128] @ W[128 x 128].
// MODE 0 (layer 1): A = [mean1 | x], W = [Wl1 ; Wr1], out = relu(C+b) -> O0[N,128]
// MODE 1 (layer 2): A = h, W = [Wl2 | Wr2],
//                   PB[N,64](bf16) = C[:,0:64] (p); O1[N,64] = C[:,64:128] + b (r)
// ROUND-4 LESSON: do NOT unroll the outer ck loop (VGPR blowout -> spill).
template <int MODE>
__global__ __launch_bounds__(256, 3) void gemm128(const float* __restrict__ A0,
                                                  const float* __restrict__ A1,
                                                  const float* __restrict__ W0,
                                                  const float* __restrict__ W1,
                                                  const float* __restrict__ bias,
                                                  float* __restrict__ O0,
                                                  float* __restrict__ O1,
                                                  unsigned short* __restrict__ PB) {
  constexpr int SAS = 36;  // sA row stride (pad 32->36: rows land on distinct banks)
  __shared__ float sA[64][SAS];
  __shared__ float sW[32][128];
  const int row0 = blockIdx.x * 64;
  const int tid = threadIdx.x;
  const int r0 = (tid >> 4) * 4;
  const int j0 = (tid & 15) * 4;

  float2 accA2[4][2];
  float2 accB2[4][2];
#pragma unroll
  for (int r = 0; r < 4; ++r)
#pragma unroll
    for (int p = 0; p < 2; ++p) {
      accA2[r][p] = make_float2(0.f, 0.f);
      accB2[r][p] = make_float2(0.f, 0.f);
    }

#pragma unroll 1   // keep ONE copy of the body (round-4 lesson)
  for (int ck = 0; ck < 4; ++ck) {
#pragma unroll
    for (int v = 0; v < 2; ++v) {
      const int vid = v * 256 + tid;
      const int rr = vid >> 3;
      const int kq = (vid & 7) * 4;
      const int grow = row0 + rr;
      float4 val = make_float4(0.f, 0.f, 0.f, 0.f);
      if (grow < NNODES) {
        if (MODE == 0) {
          const float* src = (ck < 2) ? A0 : A1;
          const int kk = (ck & 1) * 32 + kq;
          val = *(const float4*)&src[(size_t)grow * 64 + kk];
        } else {
          val = *(const float4*)&A0[(size_t)grow * 128 + ck * 32 + kq];
        }
      }
      *(float4*)&sA[rr][kq] = val;
    }
#pragma unroll
    for (int v = 0; v < 4; ++v) {
      const int vid = v * 256 + tid;
      const int kk = vid >> 5;
      const int jq = (vid & 31) * 4;
      float4 w;
      if (MODE == 0) {
        const float* src = (ck < 2) ? W0 : W1;
        const int krel = (ck & 1) * 32 + kk;
        w = *(const float4*)&src[(size_t)krel * 128 + jq];
      } else {
        const int kg = ck * 32 + kk;
        const float* src = (jq < 64) ? W0 : W1;
        const int jrel = (jq < 64) ? jq : jq - 64;
        w = *(const float4*)&src[(size_t)kg * 64 + jrel];
      }
      *(float4*)&sW[kk][jq] = w;
    }
    __syncthreads();
#pragma unroll
    for (int k4 = 0; k4 < 8; ++k4) {
      float4 a[4];
#pragma unroll
      for (int r = 0; r < 4; ++r) a[r] = *(const float4*)&sA[r0 + r][k4 * 4];
#pragma unroll
      for (int kp = 0; kp < 2; ++kp) {
        const int k_even = k4 * 4 + kp * 2;
        const float4 wlo0 = *(const float4*)&sW[k_even][j0];
        const float4 whi0 = *(const float4*)&sW[k_even][64 + j0];
        const float4 wlo1 = *(const float4*)&sW[k_even + 1][j0];
        const float4 whi1 = *(const float4*)&sW[k_even + 1][64 + j0];
#pragma unroll
        for (int r = 0; r < 4; ++r) {
          const float2 ap = (kp == 0) ? make_float2(a[r].x, a[r].y)
                                      : make_float2(a[r].z, a[r].w);
          pk_fma_lo(accA2[r][0], ap, make_float2(wlo0.x, wlo0.y));
          pk_fma_lo(accA2[r][1], ap, make_float2(wlo0.z, wlo0.w));
          pk_fma_lo(accB2[r][0], ap, make_float2(whi0.x, whi0.y));
          pk_fma_lo(accB2[r][1], ap, make_float2(whi0.z, whi0.w));
          pk_fma_hi(accA2[r][0], ap, make_float2(wlo1.x, wlo1.y));
          pk_fma_hi(accA2[r][1], ap, make_float2(wlo1.z, wlo1.w));
          pk_fma_hi(accB2[r][0], ap, make_float2(whi1.x, whi1.y));
          pk_fma_hi(accB2[r][1], ap, make_float2(whi1.z, whi1.w));
        }
      }
    }
    __syncthreads();
  }

  // --- epilogue ---
  float4 blo = make_float4(0.f, 0.f, 0.f, 0.f);
  float4 bhi;
  if (MODE == 0) {
    blo = *(const float4*)&bias[j0];
    bhi = *(const float4*)&bias[64 + j0];
  } else {
    bhi = *(const float4*)&bias[j0];  // bias applies to r (upper half)
  }
#pragma unroll
  for (int r = 0; r < 4; ++r) {
    const int grow = row0 + r0 + r;
    if (grow >= NNODES) continue;
    float4 lo = make_float4(accA2[r][0].x + blo.x, accA2[r][0].y + blo.y,
                            accA2[r][1].x + blo.z, accA2[r][1].y + blo.w);
    float4 hi = make_float4(accB2[r][0].x + bhi.x, accB2[r][0].y + bhi.y,
                            accB2[r][1].x + bhi.z, accB2[r][1].y + bhi.w);
    if (MODE == 0) {
      lo.x = fmaxf(lo.x, 0.f); lo.y = fmaxf(lo.y, 0.f);
      lo.z = fmaxf(lo.z, 0.f); lo.w = fmaxf(lo.w, 0.f);
      hi.x = fmaxf(hi.x, 0.f); hi.y = fmaxf(hi.y, 0.f);
      hi.z = fmaxf(hi.z, 0.f); hi.w = fmaxf(hi.w, 0.f);
      *(float4*)&O0[(size_t)grow * 128 + j0] = lo;
      *(float4*)&O0[(size_t)grow * 128 + 64 + j0] = hi;
    } else {
      ushort4 ob;
      ob.x = f2bf(lo.x); ob.y = f2bf(lo.y); ob.z = f2bf(lo.z); ob.w = f2bf(lo.w);
      *(ushort4*)&PB[(size_t)grow * 64 + j0] = ob;  // p as bf16 (gather operand)
      *(float4*)&O1[(size_t)grow * 64 + j0] = hi;   // r (+bl2), fp32
    }
  }
}

}  // namespace

extern "C" void kernel_launch(void* const* d_in, const int* in_sizes, int n_in,
                              void* d_out, int out_size, void* d_ws, size_t ws_size,
                              hipStream_t stream) {
  const float* x   = (const float*)d_in[0];
  const void*  ei  = d_in[1];  // edge_index, int32 or int64 (detected in-block)
  const float* Wl1 = (const float*)d_in[2];
  const float* bl1 = (const float*)d_in[3];
  const float* Wr1 = (const float*)d_in[4];
  const float* Wl2 = (const float*)d_in[5];
  const float* bl2 = (const float*)d_in[6];
  const float* Wr2 = (const float*)d_in[7];
  float* out = (float*)d_out;

  // Workspace layout (bytes):
  //   blkhist [NBUCK*SB]   int32 @ 0          (100,352 padded)
  //   rowse   [N]          int32 @ 100,352    (200,704 padded)
  //   ecol    [NBUCK*BCAP] u32   @ 301,056    (4,804,608)  packed edges -> sorted src
  //   xb      [N,64]       bf16  @ 5,105,664  (6,400,000)
  //   pb      [N,64]       bf16  @ 11,505,664 (6,400,000)
  //   mean1   [N,64]       f32   @ 17,905,664 (12,800,000)  -- reused as r
  //   h       [N,128]      f32   @ 30,705,664 (25,600,000)
  // total: 56,305,664 bytes. No memsets: every buffer fully written before read.
  char* ws = (char*)d_ws;
  int*            blkhist = (int*)(ws + 0);
  int*            rowse   = (int*)(ws + 100352);
  unsigned int*   ecol    = (unsigned int*)(ws + 301056);
  unsigned short* xb      = (unsigned short*)(ws + 5105664);
  unsigned short* pb      = (unsigned short*)(ws + 11505664);
  float*          mean1   = (float*)(ws + 17905664);
  float*          h       = (float*)(ws + 30705664);
  float*          r       = mean1;  // safe: mean1's last read (gemm128<0>) precedes gemm128<1>'s write

  // 7 dispatches: round-12 preprocessing + round-10 split GEMMs.
  histconv<<<SB + CONVB, 512, 0, stream>>>(ei, x, xb, blkhist);
  scatter_pass<<<SB, 512, 0, stream>>>(ei, blkhist, ecol);
  csr_emit<<<NBUCK, 256, 0, stream>>>(blkhist, ecol, rowse);

  constexpr int GEMM_BLOCKS = (NNODES + 63) / 64;  // 782

  seg_mean_bf<false><<<12500, 256, 0, stream>>>((const unsigned int*)xb, rowse, ecol,
                                                nullptr, mean1);
  gemm128<0><<<GEMM_BLOCKS, 256, 0, stream>>>(mean1, x, Wl1, Wr1, bl1, h, nullptr, nullptr);
  gemm128<1><<<GEMM_BLOCKS, 256, 0, stream>>>(h, nullptr, Wl2, Wr2, bl2, nullptr, r, pb);
  seg_mean_bf<true><<<12500, 256, 0, stream>>>((const unsigned int*)pb, rowse, ecol,
                                               r, out);
}

// Round 14
// 158.158 us; speedup vs baseline: 1.2153x; 1.0058x over previous
//
#include <hip/hip_runtime.h>

namespace {

constexpr int NNODES = 50000;
constexpr int NEDGES = 800000;
constexpr int NBUCK  = (NNODES + 127) / 128;  // 391 buckets of 128 dst nodes
constexpr int BCAP   = 3072;                  // bucket capacity: mean 2048, ~22 sigma slack
constexpr int SB     = 64;                    // scatter/hist blocks
constexpr int CHUNK  = NEDGES / SB;           // 12500 edges per block (exact)
constexpr int CONVB  = 1024;                  // bf16-convert blocks (in histconv)

// ROUND-6: per-address global atomic ~140ns serialized -> never >1K ops/address.
// ROUND-7: aggregation must be node-parallel (50K waves), never bucket-parallel.
// ROUND-9: seg_mean is latency/issue-bound, not byte-bound.
// ROUND-11: grid-barrier mega-fusion caps every phase at the launch grid -> REGRESSED.
// ROUND-12: fusing the two GEMMs into one block starved the pipeline. Keep split.
// ROUND-14: shave traffic (h, r in bf16) + GEMM occupancy 3->4 blocks/CU.

static __device__ __forceinline__ unsigned short f2bf(float f) {
  unsigned u = __float_as_uint(f);
  u += 0x7FFFu + ((u >> 16) & 1u);   // round-to-nearest-even
  return (unsigned short)(u >> 16);
}
static __device__ __forceinline__ float bf2f(unsigned short b) {
  return __uint_as_float((unsigned)b << 16);
}

// v_pk_fma_f32 with op_sel broadcast of one half of src0 (2 FMA/lane/cycle).
static __device__ __forceinline__ void pk_fma_lo(float2& d, const float2 a, const float2 b) {
  asm("v_pk_fma_f32 %0, %1, %2, %0 op_sel:[0,0,0] op_sel_hi:[0,1,1]"
      : "+v"(d) : "v"(a), "v"(b));
}
static __device__ __forceinline__ void pk_fma_hi(float2& d, const float2 a, const float2 b) {
  asm("v_pk_fma_f32 %0, %1, %2, %0 op_sel:[1,0,0] op_sel_hi:[1,1,1]"
      : "+v"(d) : "v"(a), "v"(b));
}

// In-block int64/int32 detection: odd 32-bit words of the first 4KB are the
// hi-halves of src values (< 50000) for int64 -> all zero; for int32 they are
// random values -> ~surely nonzero.
static __device__ __forceinline__ int detect_is64_block(const void* raw, int* s_tmp) {
  if (threadIdx.x == 0) *s_tmp = 0;
  __syncthreads();
  const unsigned int* w = (const unsigned int*)raw;
  const int nz = (w[1 + 2 * (int)(threadIdx.x & 511)] != 0u) ? 1 : 0;
  if (nz) atomicOr(s_tmp, 1);
  __syncthreads();
  return (*s_tmp == 0) ? 1 : 0;
}

// ---------------------------------------------------------------------------
// Fused launch of two INDEPENDENT jobs (no barrier needed):
//   blocks 0..SB-1      : per-block LDS histogram of dst buckets
//   blocks SB..SB+CONVB : x -> bf16 convert (grid-strided)
__global__ __launch_bounds__(512) void histconv(const void* __restrict__ raw,
                                                const float* __restrict__ xin,
                                                unsigned short* __restrict__ xb,
                                                int* __restrict__ blkhist) {
  const int tid = (int)threadIdx.x;
  if (blockIdx.x >= SB) {
    const int b = blockIdx.x - SB;
    for (int t = b * 512 + tid; t < NNODES * 64 / 4; t += CONVB * 512) {
      const float4 v = ((const float4*)xin)[t];
      ushort4 o;
      o.x = f2bf(v.x); o.y = f2bf(v.y); o.z = f2bf(v.z); o.w = f2bf(v.w);
      ((ushort4*)xb)[t] = o;
    }
    return;
  }
  __shared__ int hist[NBUCK];
  __shared__ int s_tmp;
  const int is64 = detect_is64_block(raw, &s_tmp);
  for (int i = tid; i < NBUCK; i += 512) hist[i] = 0;
  __syncthreads();
  const int b = blockIdx.x;
  const int beg = b * CHUNK, end = beg + CHUNK;
  for (int e = beg + tid; e < end; e += 512) {
    const int d = is64 ? (int)((const long long*)raw)[NEDGES + e]
                       : ((const int*)raw)[NEDGES + e];
    atomicAdd(&hist[d >> 7], 1);
  }
  __syncthreads();
  for (int i = tid; i < NBUCK; i += 512) blkhist[i * SB + b] = hist[i];
}

// Bucketed scatter; each block computes ITS OWN bucket offsets from blkhist
// (<= 63 independent L2-resident adds per bucket -> pipelined), killing the
// separate col_scan dispatch. LDS cursors only, zero global atomics.
__global__ __launch_bounds__(512) void scatter_pass(const void* __restrict__ raw,
                                                    const int* __restrict__ blkhist,
                                                    unsigned int* __restrict__ ecol) {
  __shared__ int loff[NBUCK];
  __shared__ int lcur[NBUCK];
  __shared__ int s_tmp;
  const int is64 = detect_is64_block(raw, &s_tmp);
  const int b = blockIdx.x;
  const int tid = (int)threadIdx.x;
  for (int bk = tid; bk < NBUCK; bk += 512) {
    int s = 0;
    for (int bb = 0; bb < b; ++bb) s += blkhist[bk * SB + bb];
    loff[bk] = bk * BCAP + s;
    lcur[bk] = 0;
  }
  __syncthreads();
  const int beg = b * CHUNK, end = beg + CHUNK;
  for (int e = beg + tid; e < end; e += 512) {
    int s, d;
    if (is64) {
      const long long* p = (const long long*)raw;
      s = (int)p[e];
      d = (int)p[NEDGES + e];
    } else {
      const int* p = (const int*)raw;
      s = p[e];
      d = p[NEDGES + e];
    }
    const int bk = d >> 7;
    const unsigned int val = ((unsigned int)d << 16) | (unsigned int)s;
    const int lr = atomicAdd(&lcur[bk], 1);
    ecol[loff[bk] + lr] = val;
  }
}

// One block per bucket: in-place counting sort of the bucket's packed edges
// to CSR order (src values only), computing the bucket count from blkhist;
// emits packed rowse[v] = csr_start(bucket-padded) << 9 | deg.
__global__ __launch_bounds__(256) void csr_emit(const int* __restrict__ blkhist,
                                                unsigned int* __restrict__ ecol,
                                                int* __restrict__ rowse) {
  const int bk = blockIdx.x;
  const int base = bk * 128;
  const int nloc = min(128, NNODES - base);
  const int tid = (int)threadIdx.x;
  unsigned int* eb = ecol + (size_t)bk * BCAP;

  __shared__ int dcnt[128];
  __shared__ int noff[128];
  __shared__ int ncur[128];
  __shared__ int s_cnt;
  // bucket count = sum of this bucket's 64 block-counts (wave 0)
  if (tid < 64) {
    int c = blkhist[bk * SB + tid];
#pragma unroll
    for (int off = 32; off; off >>= 1) c += __shfl_down(c, off, 64);
    if (tid == 0) s_cnt = c;
  }
  if (tid < 128) dcnt[tid] = 0;
  __syncthreads();
  const int cnt = s_cnt;               // <= BCAP = 3072 = 12*256

  // pass A: cache edges in registers + per-node counts
  unsigned int vals[12];
  int m = 0;
#pragma unroll
  for (int k = 0; k < 12; ++k) {
    const int e = tid + k * 256;
    if (e < cnt) {
      vals[k] = eb[e];
      atomicAdd(&dcnt[(vals[k] >> 16) & 127u], 1);
      m = k + 1;
    }
  }
  __syncthreads();

  // exclusive scan of dcnt[0..127]
  if (tid < 128) noff[tid] = dcnt[tid];
  __syncthreads();
#pragma unroll
  for (int off = 1; off < 128; off <<= 1) {
    int add = 0;
    if (tid < 128 && tid >= off) add = noff[tid - off];
    __syncthreads();
    if (tid < 128) noff[tid] += add;
    __syncthreads();
  }
  if (tid < 128) {
    const int excl = noff[tid] - dcnt[tid];
    noff[tid] = excl;
    ncur[tid] = 0;
    if (tid < nloc)
      rowse[base + tid] = ((bk * BCAP + excl) << 9) | dcnt[tid];
  }
  __syncthreads();

  // pass B: in-place place (all reads were reg-cached in pass A -> safe)
#pragma unroll
  for (int k = 0; k < 12; ++k) {
    if (k < m) {
      const int loc = (int)((vals[k] >> 16) & 127u);
      eb[noff[loc] + atomicAdd(&ncur[loc], 1)] = vals[k] & 0xFFFFu;
    }
  }
}

// Segment mean, 2 edges per load instruction: lane = (edge-slot, channel-pair).
// rowse[v] = start<<9 | deg (bucket-padded col space). fp32 accumulate.
// radd (FINAL) is bf16 [N,64].
template <bool FINAL>
__global__ __launch_bounds__(256) void seg_mean_bf(const unsigned int* __restrict__ xb2,
                                                   const int* __restrict__ rowse,
                                                   const unsigned int* __restrict__ col,
                                                   const unsigned int* __restrict__ radd2,
                                                   float* __restrict__ outbuf) {
  const int lane = (int)(threadIdx.x & 63);
  const int half = lane >> 5;     // edge slot (0: even edges, 1: odd)
  const int c = lane & 31;        // channel pair (chans 2c, 2c+1)
  const int wid = (blockIdx.x * blockDim.x + threadIdx.x) >> 6;
  const int nw = (gridDim.x * blockDim.x) >> 6;
  for (int v = wid; v < NNODES; v += nw) {
    const int se = rowse[v];
    const int b = se >> 9;
    const int e = b + (se & 511);
    float accx = 0.0f, accy = 0.0f;
    int i = b;
    for (; i + 8 <= e; i += 8) {  // 8 edges via 4 dual-edge gathers in flight
      const int s0 = (int)col[i + 0 + half];
      const int s1 = (int)col[i + 2 + half];
      const int s2 = (int)col[i + 4 + half];
      const int s3 = (int)col[i + 6 + half];
      const unsigned int w0 = xb2[(size_t)s0 * 32 + c];
      const unsigned int w1 = xb2[(size_t)s1 * 32 + c];
      const unsigned int w2 = xb2[(size_t)s2 * 32 + c];
      const unsigned int w3 = xb2[(size_t)s3 * 32 + c];
      accx += __uint_as_float(w0 << 16) + __uint_as_float(w1 << 16)
            + __uint_as_float(w2 << 16) + __uint_as_float(w3 << 16);
      accy += __uint_as_float(w0 & 0xFFFF0000u) + __uint_as_float(w1 & 0xFFFF0000u)
            + __uint_as_float(w2 & 0xFFFF0000u) + __uint_as_float(w3 & 0xFFFF0000u);
    }
    for (; i + 2 <= e; i += 2) {  // pair remainder
      const unsigned int w0 = xb2[(size_t)col[i + half] * 32 + c];
      accx += __uint_as_float(w0 << 16);
      accy += __uint_as_float(w0 & 0xFFFF0000u);
    }
    if (i < e && half == 0) {     // odd last edge: slot 0 only
      const unsigned int w0 = xb2[(size_t)col[i] * 32 + c];
      accx += __uint_as_float(w0 << 16);
      accy += __uint_as_float(w0 & 0xFFFF0000u);
    }
    accx += __shfl_xor(accx, 32, 64);
    accy += __shfl_xor(accy, 32, 64);
    if (half == 0) {
      const float inv = 1.0f / fmaxf((float)(se & 511), 1.0f);
      float2 res = make_float2(accx * inv, accy * inv);
      const size_t gi = (size_t)v * 32 + c;
      if (FINAL) {
        const unsigned int ra = radd2[gi];   // 2 bf16 channels
        res.x += __uint_as_float(ra << 16);
        res.y += __uint_as_float(ra & 0xFFFF0000u);
      }
      ((float2*)outbuf)[gi] = res;
    }
  }
}

// ---------------------------------------------------------------------------
// Register-tiled fp32 GEMM with v_pk_fma_f32 inner loop (split layers --
// round-12 lesson). h intermediate is bf16 (halves its round-trip traffic).
// MODE 0 (layer 1): A = [mean1 | x] (fp32), W = [Wl1 ; Wr1],
//                   HB[N,128](bf16) = relu(C + bias)
// MODE 1 (layer 2): A = HB (bf16), W = [Wl2 | Wr2],
//                   PB[N,64](bf16) = C[:,0:64] (p); RB[N,64](bf16) = C[:,64:] + bias
// ROUND-4 LESSON: do NOT unroll the outer ck loop (VGPR blowout -> spill).
// __launch_bounds__(256,4): live set ~110 VGPR -> cap 128 -> 4 blocks/CU
// (16 waves/CU; LDS 4x25.6KB = 102KB < 160KB). If VGPR_Count pins at 128
// WITH scratch traffic (spill signature), revert to (256,3).
template <int MODE>
__global__ __launch_bounds__(256, 4) void gemm128(const float* __restrict__ A0,
                                                  const float* __restrict__ A1,
                                                  const unsigned short* __restrict__ AH,
                                                  const float* __restrict__ W0,
                                                  const float* __restrict__ W1,
                                                  const float* __restrict__ bias,
                                                  unsigned short* __restrict__ HB,
                                                  unsigned short* __restrict__ PB,
                                                  unsigned short* __restrict__ RB) {
  constexpr int SAS = 36;  // sA row stride (pad 32->36: rows land on distinct banks)
  __shared__ float sA[64][SAS];
  __shared__ float sW[32][128];
  const int row0 = blockIdx.x * 64;
  const int tid = threadIdx.x;
  const int r0 = (tid >> 4) * 4;
  const int j0 = (tid & 15) * 4;

  float2 accA2[4][2];
  float2 accB2[4][2];
#pragma unroll
  for (int r = 0; r < 4; ++r)
#pragma unroll
    for (int p = 0; p < 2; ++p) {
      accA2[r][p] = make_float2(0.f, 0.f);
      accB2[r][p] = make_float2(0.f, 0.f);
    }

#pragma unroll 1   // keep ONE copy of the body (round-4 lesson)
  for (int ck = 0; ck < 4; ++ck) {
#pragma unroll
    for (int v = 0; v < 2; ++v) {
      const int vid = v * 256 + tid;
      const int rr = vid >> 3;
      const int kq = (vid & 7) * 4;
      const int grow = row0 + rr;
      float4 val = make_float4(0.f, 0.f, 0.f, 0.f);
      if (grow < NNODES) {
        if (MODE == 0) {
          const float* src = (ck < 2) ? A0 : A1;
          const int kk = (ck & 1) * 32 + kq;
          val = *(const float4*)&src[(size_t)grow * 64 + kk];
        } else {
          const ushort4 us = *(const ushort4*)&AH[(size_t)grow * 128 + ck * 32 + kq];
          val = make_float4(bf2f(us.x), bf2f(us.y), bf2f(us.z), bf2f(us.w));
        }
      }
      *(float4*)&sA[rr][kq] = val;
    }
#pragma unroll
    for (int v = 0; v < 4; ++v) {
      const int vid = v * 256 + tid;
      const int kk = vid >> 5;
      const int jq = (vid & 31) * 4;
      float4 w;
      if (MODE == 0) {
        const float* src = (ck < 2) ? W0 : W1;
        const int krel = (ck & 1) * 32 + kk;
        w = *(const float4*)&src[(size_t)krel * 128 + jq];
      } else {
        const int kg = ck * 32 + kk;
        const float* src = (jq < 64) ? W0 : W1;
        const int jrel = (jq < 64) ? jq : jq - 64;
        w = *(const float4*)&src[(size_t)kg * 64 + jrel];
      }
      *(float4*)&sW[kk][jq] = w;
    }
    __syncthreads();
#pragma unroll
    for (int k4 = 0; k4 < 8; ++k4) {
      float4 a[4];
#pragma unroll
      for (int r = 0; r < 4; ++r) a[r] = *(const float4*)&sA[r0 + r][k4 * 4];
#pragma unroll
      for (int kp = 0; kp < 2; ++kp) {
        const int k_even = k4 * 4 + kp * 2;
        const float4 wlo0 = *(const float4*)&sW[k_even][j0];
        const float4 whi0 = *(const float4*)&sW[k_even][64 + j0];
        const float4 wlo1 = *(const float4*)&sW[k_even + 1][j0];
        const float4 whi1 = *(const float4*)&sW[k_even + 1][64 + j0];
#pragma unroll
        for (int r = 0; r < 4; ++r) {
          const float2 ap = (kp == 0) ? make_float2(a[r].x, a[r].y)
                                      : make_float2(a[r].z, a[r].w);
          pk_fma_lo(accA2[r][0], ap, make_float2(wlo0.x, wlo0.y));
          pk_fma_lo(accA2[r][1], ap, make_float2(wlo0.z, wlo0.w));
          pk_fma_lo(accB2[r][0], ap, make_float2(whi0.x, whi0.y));
          pk_fma_lo(accB2[r][1], ap, make_float2(whi0.z, whi0.w));
          pk_fma_hi(accA2[r][0], ap, make_float2(wlo1.x, wlo1.y));
          pk_fma_hi(accA2[r][1], ap, make_float2(wlo1.z, wlo1.w));
          pk_fma_hi(accB2[r][0], ap, make_float2(whi1.x, whi1.y));
          pk_fma_hi(accB2[r][1], ap, make_float2(whi1.z, whi1.w));
        }
      }
    }
    __syncthreads();
  }

  // --- epilogue ---
  float4 blo = make_float4(0.f, 0.f, 0.f, 0.f);
  float4 bhi;
  if (MODE == 0) {
    blo = *(const float4*)&bias[j0];
    bhi = *(const float4*)&bias[64 + j0];
  } else {
    bhi = *(const float4*)&bias[j0];  // bias applies to r (upper half)
  }
#pragma unroll
  for (int r = 0; r < 4; ++r) {
    const int grow = row0 + r0 + r;
    if (grow >= NNODES) continue;
    float4 lo = make_float4(accA2[r][0].x + blo.x, accA2[r][0].y + blo.y,
                            accA2[r][1].x + blo.z, accA2[r][1].y + blo.w);
    float4 hi = make_float4(accB2[r][0].x + bhi.x, accB2[r][0].y + bhi.y,
                            accB2[r][1].x + bhi.z, accB2[r][1].y + bhi.w);
    if (MODE == 0) {
      ushort4 olo, ohi;
      olo.x = f2bf(fmaxf(lo.x, 0.f)); olo.y = f2bf(fmaxf(lo.y, 0.f));
      olo.z = f2bf(fmaxf(lo.z, 0.f)); olo.w = f2bf(fmaxf(lo.w, 0.f));
      ohi.x = f2bf(fmaxf(hi.x, 0.f)); ohi.y = f2bf(fmaxf(hi.y, 0.f));
      ohi.z = f2bf(fmaxf(hi.z, 0.f)); ohi.w = f2bf(fmaxf(hi.w, 0.f));
      *(ushort4*)&HB[(size_t)grow * 128 + j0] = olo;
      *(ushort4*)&HB[(size_t)grow * 128 + 64 + j0] = ohi;
    } else {
      ushort4 op, orr;
      op.x = f2bf(lo.x); op.y = f2bf(lo.y); op.z = f2bf(lo.z); op.w = f2bf(lo.w);
      orr.x = f2bf(hi.x); orr.y = f2bf(hi.y); orr.z = f2bf(hi.z); orr.w = f2bf(hi.w);
      *(ushort4*)&PB[(size_t)grow * 64 + j0] = op;   // p (gather operand)
      *(ushort4*)&RB[(size_t)grow * 64 + j0] = orr;  // r (+bl2)
    }
  }
}

}  // namespace

extern "C" void kernel_launch(void* const* d_in, const int* in_sizes, int n_in,
                              void* d_out, int out_size, void* d_ws, size_t ws_size,
                              hipStream_t stream) {
  const float* x   = (const float*)d_in[0];
  const void*  ei  = d_in[1];  // edge_index, int32 or int64 (detected in-block)
  const float* Wl1 = (const float*)d_in[2];
  const float* bl1 = (const float*)d_in[3];
  const float* Wr1 = (const float*)d_in[4];
  const float* Wl2 = (const float*)d_in[5];
  const float* bl2 = (const float*)d_in[6];
  const float* Wr2 = (const float*)d_in[7];
  float* out = (float*)d_out;

  // Workspace layout (bytes):
  //   blkhist [NBUCK*SB]   int32 @ 0          (100,352 padded)
  //   rowse   [N]          int32 @ 100,352    (200,704 padded)
  //   ecol    [NBUCK*BCAP] u32   @ 301,056    (4,804,608)  packed edges -> sorted src
  //   xb      [N,64]       bf16  @ 5,105,664  (6,400,000)
  //   pb      [N,64]       bf16  @ 11,505,664 (6,400,000)
  //   mean1   [N,64]       f32   @ 17,905,664 (12,800,000)
  //   hb      [N,128]      bf16  @ 30,705,664 (12,800,000)
  //   rb      [N,64]       bf16  @ 43,505,664 (6,400,000)
  // total: 49,905,664 bytes. No memsets: every buffer fully written before read.
  char* ws = (char*)d_ws;
  int*            blkhist = (int*)(ws + 0);
  int*            rowse   = (int*)(ws + 100352);
  unsigned int*   ecol    = (unsigned int*)(ws + 301056);
  unsigned short* xb      = (unsigned short*)(ws + 5105664);
  unsigned short* pb      = (unsigned short*)(ws + 11505664);
  float*          mean1   = (float*)(ws + 17905664);
  unsigned short* hb      = (unsigned short*)(ws + 30705664);
  unsigned short* rb      = (unsigned short*)(ws + 43505664);

  // 7 dispatches: round-12 preprocessing + split bf16-intermediate GEMMs.
  histconv<<<SB + CONVB, 512, 0, stream>>>(ei, x, xb, blkhist);
  scatter_pass<<<SB, 512, 0, stream>>>(ei, blkhist, ecol);
  csr_emit<<<NBUCK, 256, 0, stream>>>(blkhist, ecol, rowse);

  constexpr int GEMM_BLOCKS = (NNODES + 63) / 64;  // 782

  seg_mean_bf<false><<<12500, 256, 0, stream>>>((const unsigned int*)xb, rowse, ecol,
                                                nullptr, mean1);
  gemm128<0><<<GEMM_BLOCKS, 256, 0, stream>>>(mean1, x, nullptr, Wl1, Wr1, bl1,
                                              hb, nullptr, nullptr);
  gemm128<1><<<GEMM_BLOCKS, 256, 0, stream>>>(nullptr, nullptr, hb, Wl2, Wr2, bl2,
                                              nullptr, pb, rb);
  seg_mean_bf<true><<<12500, 256, 0, stream>>>((const unsigned int*)pb, rowse, ecol,
                                               (const unsigned int*)rb, out);
}